// Round 7
// baseline (260.553 us; speedup 1.0000x reference)
//
#include <hip/hip_runtime.h>
#include <hip/hip_bf16.h>
#include <stdint.h>

typedef unsigned short ushort_t;
typedef __attribute__((ext_vector_type(8))) short short8;
typedef __attribute__((ext_vector_type(4))) float f32x4;
typedef __attribute__((ext_vector_type(2))) float f32x2;

__device__ __forceinline__ float b2f(ushort_t u) {
    union { uint32_t i; float f; } v; v.i = ((uint32_t)u) << 16; return v.f;
}
__device__ __forceinline__ ushort_t f2b(float f) {
    union { float f; uint32_t i; } v; v.f = f;
    uint32_t r = v.i + 0x7fff + ((v.i >> 16) & 1);
    return (ushort_t)(r >> 16);
}

#if __has_builtin(__builtin_amdgcn_exp2f)
#define EXP2(x) __builtin_amdgcn_exp2f(x)
#else
#define EXP2(x) __expf((x) * 0.69314718056f)
#endif

// async global->LDS, 16B per lane; lds base must be wave-uniform
__device__ __forceinline__ void ll16(const ushort_t* g, ushort_t* l) {
    __builtin_amdgcn_global_load_lds(
        (const __attribute__((address_space(1))) uint32_t*)g,
        (__attribute__((address_space(3))) uint32_t*)l, 16, 0, 0);
}

// DPP cross-lane add (VALU pipe)
template <int CTRL>
__device__ __forceinline__ float dpp_add(float p) {
    int v = __builtin_amdgcn_update_dpp(0, __float_as_int(p), CTRL, 0xF, 0xF, true);
    return p + __int_as_float(v);
}
#define DPP_XOR1 0xB1
#define DPP_XOR2 0x4E
#define DPP_HMIR 0x141

// ---------------------------------------------------------------------------
// Coalesced epilogues: wave's 16x64 output group via private LDS scratch.
// ---------------------------------------------------------------------------
__device__ __forceinline__ void epi_wave_f32(
    float* sw, const f32x4* accg, float* dst0, int ldc, int lane)
{
    const int quad = lane >> 4, lr = lane & 15;
#pragma unroll
    for (int j = 0; j < 4; j++)
#pragma unroll
        for (int r = 0; r < 4; r++)
            sw[(quad * 4 + r) * 64 + j * 16 + lr] = accg[j][r];
    __asm__ volatile("s_waitcnt lgkmcnt(0)" ::: "memory");
#pragma unroll
    for (int t = 0; t < 4; t++) {
        int row = t * 4 + quad;
        float4 v = *(const float4*)(&sw[row * 64 + lr * 4]);
        *(float4*)(dst0 + (size_t)row * ldc + lr * 4) = v;
    }
}

__device__ __forceinline__ void epi_wave_b16(
    float* sw, const f32x4* accg, ushort_t* dst0, int ldc, int lane)
{
    const int quad = lane >> 4, lr = lane & 15;
#pragma unroll
    for (int j = 0; j < 4; j++)
#pragma unroll
        for (int r = 0; r < 4; r++)
            sw[(quad * 4 + r) * 64 + j * 16 + lr] = accg[j][r];
    __asm__ volatile("s_waitcnt lgkmcnt(0)" ::: "memory");
#pragma unroll
    for (int t = 0; t < 4; t++) {
        int row = t * 4 + quad;
        float4 v = *(const float4*)(&sw[row * 64 + lr * 4]);
        ushort4 o; o.x = f2b(v.x); o.y = f2b(v.y); o.z = f2b(v.z); o.w = f2b(v.w);
        *(ushort4*)(dst0 + (size_t)row * ldc + lr * 4) = o;
    }
}

// ---------------------------------------------------------------------------
// Fused multi-tensor fp32 -> bf16 cast (7 segments, 1 launch)
// ---------------------------------------------------------------------------
struct CastSeg { const float4* src; ushort4* dst; };
struct CastArgs { CastSeg seg[7]; int start[8]; };

__global__ __launch_bounds__(256) void cast_multi(CastArgs a)
{
    int g = blockIdx.x * 256 + threadIdx.x;
    if (g >= a.start[7]) return;
    int s = 0;
#pragma unroll
    for (int i = 1; i < 7; i++) s += (g >= a.start[i]);
    int i = g - a.start[s];
    float4 v = a.seg[s].src[i];
    ushort4 o;
    o.x = f2b(v.x); o.y = f2b(v.y); o.z = f2b(v.z); o.w = f2b(v.w);
    a.seg[s].dst[i] = o;
}

#define BK 32

// ---------------------------------------------------------------------------
// G1 v13: BM=64 tiles -> 1024 blocks, XCD-swizzled, double-buffered.
// ---------------------------------------------------------------------------
__global__ __launch_bounds__(256, 4) void gemm_g1(
    const ushort_t* __restrict__ A, int lda,
    const ushort_t* __restrict__ B, int ldb,
    ushort_t* __restrict__ Cout, int ldc, int Kd)
{
    __shared__ ushort_t As[2][64 * BK];
    __shared__ ushort_t Bs[2][128 * BK];
    __shared__ float sepi[4][1024];

    // XCD swizzle: nwg = 32*32 = 1024, q = 128
    const int flat = blockIdx.y * 32 + blockIdx.x;
    const int swz  = (flat & 7) * 128 + (flat >> 3);
    const int n0   = (swz & 31) * 128;
    const int m0   = (swz >> 5) * 64;

    const int tid  = threadIdx.x;
    const int wv   = tid >> 6;
    const int lane = tid & 63;
    const int wm   = (wv >> 1) * 32;
    const int wn   = (wv & 1) * 64;
    const int lr   = lane & 15;
    const int quad = lane >> 4;

    f32x4 acc[2][4];
#pragma unroll
    for (int i = 0; i < 2; i++)
#pragma unroll
        for (int j = 0; j < 4; j++) acc[i][j] = f32x4{0.f, 0.f, 0.f, 0.f};

    const int srA = wv * 16 + (lane >> 2);
    const int srB = wv * 32 + (lane >> 2);
    const int sc  = (lane & 3) * 8;

    auto stage = [&](int bf_, int k0) {
        ll16(A + (size_t)(m0 + srA) * lda + k0 + sc,      &As[bf_][wv * 512]);
        ll16(B + (size_t)(n0 + srB) * ldb + k0 + sc,      &Bs[bf_][wv * 1024]);
        ll16(B + (size_t)(n0 + srB + 16) * ldb + k0 + sc, &Bs[bf_][wv * 1024 + 512]);
    };

    const int nk = Kd / BK;
    stage(0, 0);
    __syncthreads();

    for (int t = 0; t < nk; ++t) {
        const int buf = t & 1;
        if (t + 1 < nk) stage(buf ^ 1, (t + 1) * BK);

        short8 af[2], bfr[4];
#pragma unroll
        for (int i = 0; i < 2; i++)
            af[i] = *(const short8*)(&As[buf][(wm + i * 16 + lr) * BK + quad * 8]);
#pragma unroll
        for (int j = 0; j < 4; j++)
            bfr[j] = *(const short8*)(&Bs[buf][(wn + j * 16 + lr) * BK + quad * 8]);
#pragma unroll
        for (int i = 0; i < 2; i++)
#pragma unroll
            for (int j = 0; j < 4; j++)
                acc[i][j] = __builtin_amdgcn_mfma_f32_16x16x32_bf16(af[i], bfr[j], acc[i][j], 0, 0, 0);
        __syncthreads();
    }

#pragma unroll
    for (int g = 0; g < 2; g++)
        epi_wave_b16(sepi[wv], acc[g],
                     Cout + (size_t)(m0 + wm + g * 16) * ldc + n0 + wn, ldc, lane);
}

// ---------------------------------------------------------------------------
// G4 v14: combine fused, split-K=2 (R7: reverted from SK4 — occupancy proved
// near-worthless in R6, SK2 halves partial+reduce traffic), XCD-swizzled.
// ---------------------------------------------------------------------------
__global__ __launch_bounds__(256, 4) void gemm_g4(
    const ushort_t* __restrict__ yfp, const ushort_t* __restrict__ ybp,
    const ushort_t* __restrict__ B, int ldb,
    float* __restrict__ p01)
{
    __shared__ ushort_t As[2][64 * BK];
    __shared__ ushort_t Bs[2][128 * BK];
    __shared__ float sepi[4][1024];

    // XCD swizzle: nwg = 8*32*2 = 512, q = 64
    const int flat = (blockIdx.z * 32 + blockIdx.y) * 8 + blockIdx.x;
    const int swz  = (flat & 7) * 64 + (flat >> 3);
    const int n0   = (swz & 7) * 128;
    const int m0   = ((swz >> 3) & 31) * 64;
    const int kz   = swz >> 8;

    const int tid  = threadIdx.x;
    const int kbase = kz * 1024;
    const int wv   = tid >> 6;
    const int lane = tid & 63;
    const int wm   = (wv >> 1) * 32;
    const int wn   = (wv & 1) * 64;
    const int lr   = lane & 15;
    const int quad = lane >> 4;

    f32x4 acc[2][4];
#pragma unroll
    for (int i = 0; i < 2; i++)
#pragma unroll
        for (int j = 0; j < 4; j++) acc[i][j] = f32x4{0.f, 0.f, 0.f, 0.f};

    const int srA = wv * 16 + (lane >> 2);
    const int srB = wv * 32 + (lane >> 2);
    const int sc  = (lane & 3) * 8;

    // A row -> forward/backward y rows (combine fusion)
    const int arow = m0 + srA;
    const int t_   = arow & 511;
    const size_t yf_off = (size_t)arow * 2048;
    const size_t yb_off = (size_t)(arow - t_ + 511 - t_) * 2048;

    uint4 ra, rb;
    auto loadA = [&](int k0) {
        ra = *(const uint4*)(yfp + yf_off + kbase + k0 + sc);
        rb = *(const uint4*)(ybp + yb_off + kbase + k0 + sc);
    };
    auto writeA = [&](int bf_) {
        const uint32_t pa[4] = { ra.x, ra.y, ra.z, ra.w };
        const uint32_t pb[4] = { rb.x, rb.y, rb.z, rb.w };
        uint32_t w[4];
#pragma unroll
        for (int k = 0; k < 4; k++) {
            float a0 = b2f((ushort_t)(pa[k] & 0xffff));
            float a1 = b2f((ushort_t)(pa[k] >> 16));
            float c0 = b2f((ushort_t)(pb[k] & 0xffff));
            float c1 = b2f((ushort_t)(pb[k] >> 16));
            w[k] = (uint32_t)f2b(0.5f * (a0 + c0)) |
                   ((uint32_t)f2b(0.5f * (a1 + c1)) << 16);
        }
        *(uint4*)(&As[bf_][wv * 512 + (lane >> 2) * 32 + (lane & 3) * 8]) =
            make_uint4(w[0], w[1], w[2], w[3]);
    };
    auto stageB = [&](int bf_, int k0) {
        ll16(B + (size_t)(n0 + srB) * ldb + kbase + k0 + sc,      &Bs[bf_][wv * 1024]);
        ll16(B + (size_t)(n0 + srB + 16) * ldb + kbase + k0 + sc, &Bs[bf_][wv * 1024 + 512]);
    };

    const int nk = 1024 / BK;
    loadA(0);
    stageB(0, 0);
    writeA(0);
    __syncthreads();

    for (int t = 0; t < nk; ++t) {
        const int buf = t & 1;
        if (t + 1 < nk) {
            loadA((t + 1) * BK);              // issue early (hides under MFMA)
            stageB(buf ^ 1, (t + 1) * BK);
        }

        short8 af[2], bfr[4];
#pragma unroll
        for (int i = 0; i < 2; i++)
            af[i] = *(const short8*)(&As[buf][(wm + i * 16 + lr) * BK + quad * 8]);
#pragma unroll
        for (int j = 0; j < 4; j++)
            bfr[j] = *(const short8*)(&Bs[buf][(wn + j * 16 + lr) * BK + quad * 8]);
#pragma unroll
        for (int i = 0; i < 2; i++)
#pragma unroll
            for (int j = 0; j < 4; j++)
                acc[i][j] = __builtin_amdgcn_mfma_f32_16x16x32_bf16(af[i], bfr[j], acc[i][j], 0, 0, 0);

        if (t + 1 < nk) writeA(buf ^ 1);      // write late (after compute)
        __syncthreads();
    }

    float* Cout = p01 + (size_t)kz * 2048 * 1024;
#pragma unroll
    for (int g = 0; g < 2; g++)
        epi_wave_f32(sepi[wv], acc[g],
                     Cout + (size_t)(m0 + wm + g * 16) * 1024 + n0 + wn, 1024, lane);
}

__global__ __launch_bounds__(256) void reduce_g4(
    const float4* __restrict__ p01, float4* __restrict__ out)
{
    int g = blockIdx.x * 256 + threadIdx.x;   // 524288 total
    const int S = 2048 * 1024 / 4;
    float4 a = p01[g], b = p01[g + S];
    float4 o;
    o.x = a.x + b.x; o.y = a.y + b.y; o.z = a.z + b.z; o.w = a.w + b.w;
    out[g] = o;
}

// ---------------------------------------------------------------------------
// G2 v14: split-K 8->4 (R7: halves partial traffic; K=512/block, 16 iters).
// grid (4, 32, 2) = 256 blocks, XCD-swizzled.
// ---------------------------------------------------------------------------
__global__ __launch_bounds__(256, 4) void gemm_g2(
    const ushort_t* __restrict__ xc, const ushort_t* __restrict__ wx,
    float* __restrict__ part)
{
    __shared__ ushort_t As[2][64 * BK];
    __shared__ ushort_t Bs[2][128 * BK];
    __shared__ float sepi[4][1024];

    // XCD swizzle: nwg = 4*32*2 = 256, q = 32
    const int flat = (blockIdx.z * 32 + blockIdx.y) * 4 + blockIdx.x;
    const int swz  = (flat & 7) * 32 + (flat >> 3);
    const int sk   = swz & 3;
    const int mb   = (swz >> 2) & 31;
    const int br   = swz >> 7;

    const ushort_t* A = xc + (size_t)br * 2048 * 2048;
    const ushort_t* B = wx + (size_t)br * 96 * 2048;
    float* C = part + (size_t)(sk * 2 + br) * 2048 * 96;
    const int m0 = mb * 64;
    const int kb = sk * 512;

    const int tid  = threadIdx.x;
    const int wv   = tid >> 6;
    const int lane = tid & 63;
    const int wm   = (wv >> 1) * 32;
    const int wn   = (wv & 1) * 64;
    const int lr   = lane & 15;
    const int quad = lane >> 4;

    f32x4 acc[2][4];
#pragma unroll
    for (int i = 0; i < 2; i++)
#pragma unroll
        for (int j = 0; j < 4; j++) acc[i][j] = f32x4{0.f, 0.f, 0.f, 0.f};

    const int srA = wv * 16 + (lane >> 2);
    const int srB = wv * 32 + (lane >> 2);
    const int sc  = (lane & 3) * 8;

    auto stage = [&](int bf_, int k0) {
        ll16(A + (size_t)(m0 + srA) * 2048 + k0 + sc,      &As[bf_][wv * 512]);
        ll16(B + (size_t)(srB) * 2048 + k0 + sc,           &Bs[bf_][wv * 1024]);
        ll16(B + (size_t)(srB + 16) * 2048 + k0 + sc,      &Bs[bf_][wv * 1024 + 512]);
    };

    stage(0, kb);
    __syncthreads();

    for (int t = 0; t < 16; ++t) {
        const int buf = t & 1;
        if (t + 1 < 16) stage(buf ^ 1, kb + (t + 1) * BK);

        short8 af[2], bfr[4];
#pragma unroll
        for (int i = 0; i < 2; i++)
            af[i] = *(const short8*)(&As[buf][(wm + i * 16 + lr) * BK + quad * 8]);
#pragma unroll
        for (int j = 0; j < 4; j++)
            bfr[j] = *(const short8*)(&Bs[buf][(wn + j * 16 + lr) * BK + quad * 8]);
#pragma unroll
        for (int i = 0; i < 2; i++)
#pragma unroll
            for (int j = 0; j < 4; j++)
                acc[i][j] = __builtin_amdgcn_mfma_f32_16x16x32_bf16(af[i], bfr[j], acc[i][j], 0, 0, 0);
        __syncthreads();
    }

    float* sw = sepi[wv];
#pragma unroll
    for (int g = 0; g < 2; g++) {
#pragma unroll
        for (int j = 0; j < 4; j++)
#pragma unroll
            for (int r = 0; r < 4; r++)
                sw[(quad * 4 + r) * 64 + j * 16 + lr] = acc[g][j][r];
        __asm__ volatile("s_waitcnt lgkmcnt(0)" ::: "memory");
        int col = wn + lr * 4;
#pragma unroll
        for (int t = 0; t < 4; t++) {
            int row = t * 4 + quad;
            if (col < 96) {
                float4 v = *(const float4*)(&sw[row * 64 + lr * 4]);
                *(float4*)(C + (size_t)(m0 + wm + g * 16 + row) * 96 + col) = v;
            }
        }
    }
}

__global__ __launch_bounds__(256) void reduce_dbc(
    const float4* __restrict__ part, ushort4* __restrict__ dbc16)
{
    int g = blockIdx.x * 256 + threadIdx.x;   // 98304 total
    const int S = 2 * 2048 * 96 / 4;
    float4 r = part[g];
#pragma unroll
    for (int i = 1; i < 4; i++) {
        float4 p = part[g + i * S];
        r.x += p.x; r.y += p.y; r.z += p.z; r.w += p.w;
    }
    ushort4 o; o.x = f2b(r.x); o.y = f2b(r.y); o.z = f2b(r.z); o.w = f2b(r.w);
    dbc16[g] = o;
}

// ---------------------------------------------------------------------------
// G3 v13: BM=64 -> grid (16, 32, 2) = 1024 blocks, XCD-swizzled.
// ---------------------------------------------------------------------------
__global__ __launch_bounds__(256, 4) void gemm_g3(
    const ushort_t* __restrict__ dbc16, const ushort_t* __restrict__ wdt,
    ushort_t* __restrict__ delta,
    const float* __restrict__ bdt_f, const float* __restrict__ bdt_b)
{
    __shared__ ushort_t As[2][64 * BK];
    __shared__ ushort_t Bs[2][128 * BK];
    __shared__ float sepi[4][1024];

    // XCD swizzle: nwg = 16*32*2 = 1024, q = 128
    const int flat = (blockIdx.z * 32 + blockIdx.y) * 16 + blockIdx.x;
    const int swz  = (flat & 7) * 128 + (flat >> 3);
    const int n0   = (swz & 15) * 128;
    const int m0   = ((swz >> 4) & 31) * 64;
    const int br   = swz >> 9;

    const ushort_t* A = dbc16 + (size_t)br * 2048 * 96;
    const ushort_t* B = wdt + (size_t)br * 2048 * 64;
    ushort_t* C = delta + (size_t)br * 2048 * 2048;
    const float* bias = br ? bdt_b : bdt_f;

    const int tid  = threadIdx.x;
    const int wv   = tid >> 6;
    const int lane = tid & 63;
    const int wm   = (wv >> 1) * 32;
    const int wn   = (wv & 1) * 64;
    const int lr   = lane & 15;
    const int quad = lane >> 4;

    f32x4 acc[2][4];
#pragma unroll
    for (int i = 0; i < 2; i++)
#pragma unroll
        for (int j = 0; j < 4; j++) acc[i][j] = f32x4{0.f, 0.f, 0.f, 0.f};

    const int srA = wv * 16 + (lane >> 2);
    const int srB = wv * 32 + (lane >> 2);
    const int sc  = (lane & 3) * 8;

    auto stage = [&](int bf_, int k0) {
        ll16(A + (size_t)(m0 + srA) * 96 + k0 + sc,       &As[bf_][wv * 512]);
        ll16(B + (size_t)(n0 + srB) * 64 + k0 + sc,       &Bs[bf_][wv * 1024]);
        ll16(B + (size_t)(n0 + srB + 16) * 64 + k0 + sc,  &Bs[bf_][wv * 1024 + 512]);
    };

    stage(0, 0);
    __syncthreads();

    for (int t = 0; t < 2; ++t) {
        const int buf = t & 1;
        if (t + 1 < 2) stage(buf ^ 1, (t + 1) * BK);

        short8 af[2], bfr[4];
#pragma unroll
        for (int i = 0; i < 2; i++)
            af[i] = *(const short8*)(&As[buf][(wm + i * 16 + lr) * BK + quad * 8]);
#pragma unroll
        for (int j = 0; j < 4; j++)
            bfr[j] = *(const short8*)(&Bs[buf][(wn + j * 16 + lr) * BK + quad * 8]);
#pragma unroll
        for (int i = 0; i < 2; i++)
#pragma unroll
            for (int j = 0; j < 4; j++)
                acc[i][j] = __builtin_amdgcn_mfma_f32_16x16x32_bf16(af[i], bfr[j], acc[i][j], 0, 0, 0);
        __syncthreads();
    }

    float bn[4];
#pragma unroll
    for (int j = 0; j < 4; j++) bn[j] = bias[n0 + wn + j * 16 + lr];
#pragma unroll
    for (int g = 0; g < 2; g++)
#pragma unroll
        for (int j = 0; j < 4; j++)
#pragma unroll
            for (int r = 0; r < 4; r++) {
                float x = acc[g][j][r] + bn[j];
                float sp = fmaxf(x, 0.f) + __logf(1.f + __expf(-fabsf(x)));
                acc[g][j][r] = sp;
            }

#pragma unroll
    for (int g = 0; g < 2; g++)
        epi_wave_b16(sepi[wv], acc[g],
                     C + (size_t)(m0 + wm + g * 16) * 2048 + n0 + wn, 2048, lane);
}

// ---------------------------------------------------------------------------
// Causal depthwise conv (K=4) + bias + silu, v3: vectorized + XCD swizzle
// (consecutive-t blocks share 3 of 4 input rows -> keep them on one XCD L2).
// ---------------------------------------------------------------------------
__global__ __launch_bounds__(256) void conv_silu_kernel(
    const ushort_t* __restrict__ xz,
    const float* __restrict__ w_f, const float* __restrict__ cb_f,
    const float* __restrict__ w_b, const float* __restrict__ cb_b,
    ushort_t* __restrict__ xc16)
{
    // XCD swizzle: nwg = 4096, q = 512 (contiguous t-span per XCD)
    const int flat = blockIdx.x;
    const int blk  = (flat & 7) * 512 + (flat >> 3);
    int g = blk * 256 + threadIdx.x;          // 1,048,576 total
    int e0 = (g & 255) * 8;
    int t  = (g >> 8) & 511;
    int b  = (g >> 17) & 3;
    int br = g >> 19;

    const float* w  = br ? w_b  : w_f;
    const float* cb = br ? cb_b : cb_f;

    // taps (zeroed when t-3+k < 0; b2f(0) == 0.0f)
    uint32_t tv[4][4];
#pragma unroll
    for (int k = 0; k < 4; k++) {
        int tp = t - 3 + k;
        if (tp >= 0) {                          // wave-uniform (t const per wave)
            int row = br ? (511 - tp) : tp;
            uint4 xv = *(const uint4*)(xz + ((size_t)(b * 512 + row)) * 4096 + e0);
            tv[k][0] = xv.x; tv[k][1] = xv.y; tv[k][2] = xv.z; tv[k][3] = xv.w;
        } else {
            tv[k][0] = 0; tv[k][1] = 0; tv[k][2] = 0; tv[k][3] = 0;
        }
    }

    float4 cbv0 = *(const float4*)(cb + e0);
    float4 cbv1 = *(const float4*)(cb + e0 + 4);
    const float cbs[8] = { cbv0.x, cbv0.y, cbv0.z, cbv0.w,
                           cbv1.x, cbv1.y, cbv1.z, cbv1.w };

    uint32_t op[4];
#pragma unroll
    for (int q = 0; q < 4; q++) {
        float4 wA = *(const float4*)(w + (e0 + 2 * q) * 4);
        float4 wB = *(const float4*)(w + (e0 + 2 * q + 1) * 4);
        float a0 = cbs[2 * q]
                 + wA.x * b2f((ushort_t)(tv[0][q] & 0xffff))
                 + wA.y * b2f((ushort_t)(tv[1][q] & 0xffff))
                 + wA.z * b2f((ushort_t)(tv[2][q] & 0xffff))
                 + wA.w * b2f((ushort_t)(tv[3][q] & 0xffff));
        float a1 = cbs[2 * q + 1]
                 + wB.x * b2f((ushort_t)(tv[0][q] >> 16))
                 + wB.y * b2f((ushort_t)(tv[1][q] >> 16))
                 + wB.z * b2f((ushort_t)(tv[2][q] >> 16))
                 + wB.w * b2f((ushort_t)(tv[3][q] >> 16));
        float s0 = a0 / (1.f + __expf(-a0));
        float s1 = a1 / (1.f + __expf(-a1));
        op[q] = (uint32_t)f2b(s0) | ((uint32_t)f2b(s1) << 16);
    }
    *(uint4*)(xc16 + (size_t)g * 8) = make_uint4(op[0], op[1], op[2], op[3]);
}

// ---------------------------------------------------------------------------
// Selective scan v10 (unchanged).
// ---------------------------------------------------------------------------
__global__ __launch_bounds__(256, 4) void scan_kernel(
    const ushort_t* __restrict__ delta,   // [2][B][L][ED] bf16
    const ushort_t* __restrict__ xc,      // [2][B][L][ED] bf16
    const ushort_t* __restrict__ dbc16,   // [2][B][L][96] bf16
    const ushort_t* __restrict__ xz,      // [B][L][4096] bf16 (z half)
    const float* __restrict__ Alog_f, const float* __restrict__ Alog_b,
    const float* __restrict__ Dp_f,   const float* __restrict__ Dp_b,
    ushort_t* __restrict__ yf, ushort_t* __restrict__ yb)
{
    const int blk = blockIdx.x;            // 0..511
    const int eg = blk & 63;
    const int b  = (blk >> 6) & 3;
    const int br = blk >> 8;
    const int e0 = eg * 32;

    const int tid = threadIdx.x;
    const int n2  = tid & 7;               // hot-loop: state index
    const int el  = tid >> 3;              // hot-loop: element 0..31
    const int e   = e0 + el;

    const float* Alog = br ? Alog_b : Alog_f;
    const float* Dpp  = br ? Dp_b   : Dp_f;
    // pre-scaled by log2(e) so dA = exp2(d * A); packed pair (n2, n2+8)
    f32x2 a01;
    a01.x = -__expf(Alog[e * 16 + n2]) * 1.44269504f;
    a01.y = -__expf(Alog[e * 16 + n2 + 8]) * 1.44269504f;

    size_t tb = ((size_t)br * 4 + b) * 512;
    const ushort_t* dlt  = delta + tb * 2048;
    const ushort_t* xcb  = xc    + tb * 2048;
    const ushort_t* dbcb = dbc16 + tb * 96;
    ushort_t* y = (br ? yb : yf) + (size_t)b * 512 * 2048;

    __shared__ float sd [2][32][36];       // d[e][t^key(e)]
    __shared__ float sdx[2][32][36];       // (d*x)[e][t^key(e)]
    __shared__ float sBp[2][8][34][2];     // {B[n],B[n+8]}[t] packed pairs
    __shared__ float sCp[2][8][34][2];     // {C[n],C[n+8]}[t]
    __shared__ float sy [2][32][33];       // y[t][e], ping-pong

    const int stt = tid >> 3;              // staging: t within chunk 0..31
    const int seg = tid & 7;               // staging: 4-elem column group
    const int sg4 = seg * 4;
    const int sdk = (seg & 3) * 8;         // store-side xor key (rows seg*4..+3)

    float4 rD = *(const float4*)(Dpp + e0 + sg4);

    uint2 rdx, rx, rbc, rz;
    uint2 rx_c, rx_f, rz_c, rz_f;

    auto load_regs = [&](int c) {
        int row = c * 32 + stt;
        rdx = *(const uint2*)(dlt + (size_t)row * 2048 + e0 + sg4);
        rx  = *(const uint2*)(xcb + (size_t)row * 2048 + e0 + sg4);
        rbc = *(const uint2*)(dbcb + (size_t)row * 96 + 64 + sg4);
        int orow = br ? (511 - row) : row;
        rz  = *(const uint2*)(xz + ((size_t)(b * 512 + orow)) * 4096 + 2048 + e0 + sg4);
    };
    auto write_lds = [&](int buf) {
        const uint32_t dw[2] = { rdx.x, rdx.y };
        const uint32_t xw[2] = { rx.x, rx.y };
        const int col = stt ^ sdk;
#pragma unroll
        for (int k = 0; k < 2; k++) {
            float d0 = b2f((ushort_t)(dw[k] & 0xffff));
            float d1 = b2f((ushort_t)(dw[k] >> 16));
            float x0 = b2f((ushort_t)(xw[k] & 0xffff));
            float x1 = b2f((ushort_t)(xw[k] >> 16));
            sd [buf][sg4 + 2 * k][col]     = d0;
            sd [buf][sg4 + 2 * k + 1][col] = d1;
            sdx[buf][sg4 + 2 * k][col]     = d0 * x0;
            sdx[buf][sg4 + 2 * k + 1][col] = d1 * x1;
        }
        // B/C interleaved pairs: seg 0..3 -> B n=(seg*4..+3), seg 4..7 -> C
        float* arr = (seg < 4) ? &sBp[buf][0][0][0] : &sCp[buf][0][0][0];
        const int nb = (seg & 3) * 4;
        const uint32_t bw[2] = { rbc.x, rbc.y };
#pragma unroll
        for (int k = 0; k < 2; k++) {
            int na = nb + 2 * k, nbd = nb + 2 * k + 1;
            arr[(na  & 7) * 68 + stt * 2 + (na  >> 3)] = b2f((ushort_t)(bw[k] & 0xffff));
            arr[(nbd & 7) * 68 + stt * 2 + (nbd >> 3)] = b2f((ushort_t)(bw[k] >> 16));
        }
    };
    auto flush = [&](int cm1) {
        const int bufm1 = cm1 & 1;
        int row = cm1 * 32 + stt;
        const uint32_t zw[2] = { rz_f.x, rz_f.y };
        float zv[4];
#pragma unroll
        for (int k = 0; k < 2; k++) {
            zv[2 * k]     = b2f((ushort_t)(zw[k] & 0xffff));
            zv[2 * k + 1] = b2f((ushort_t)(zw[k] >> 16));
        }
        float pv[4];
#pragma unroll
        for (int k = 0; k < 4; k++) pv[k] = sy[bufm1][stt][sg4 + k];
        const uint32_t xw[2] = { rx_f.x, rx_f.y };
        float xvv[4];
#pragma unroll
        for (int k = 0; k < 2; k++) {
            xvv[2 * k]     = b2f((ushort_t)(xw[k] & 0xffff));
            xvv[2 * k + 1] = b2f((ushort_t)(xw[k] >> 16));
        }
        const float Dv[4] = { rD.x, rD.y, rD.z, rD.w };
        uint32_t op[2];
#pragma unroll
        for (int k = 0; k < 2; k++) {
            float ga = (pv[2 * k]     + Dv[2 * k]     * xvv[2 * k])     *
                       (zv[2 * k]     / (1.f + __expf(-zv[2 * k])));
            float gb = (pv[2 * k + 1] + Dv[2 * k + 1] * xvv[2 * k + 1]) *
                       (zv[2 * k + 1] / (1.f + __expf(-zv[2 * k + 1])));
            op[k] = (uint32_t)f2b(ga) | ((uint32_t)f2b(gb) << 16);
        }
        *(uint2*)(y + (size_t)row * 2048 + e0 + sg4) = make_uint2(op[0], op[1]);
    };

    f32x2 h01 = f32x2{0.f, 0.f};
    const int elk = ((el >> 2) & 3) * 8;   // read-side xor key (matches sdk)

    load_regs(0);
    write_lds(0);
    rx_c = rx; rz_c = rz;

    for (int c = 0; c < 16; ++c) {
        if (c < 15) load_regs(c + 1);
        __syncthreads();
        const int buf = c & 1;

        auto LDQ = [&](int tq, f32x4& dv, f32x4& dxv, f32x4& bq0, f32x4& bq1,
                       f32x4& cq0, f32x4& cq1) {
            const int tc = tq ^ elk;
            dv  = *(const f32x4*)(&sd [buf][el][tc]);
            dxv = *(const f32x4*)(&sdx[buf][el][tc]);
            bq0 = *(const f32x4*)(&sBp[buf][n2][tq][0]);      // pairs t, t+1
            bq1 = *(const f32x4*)(&sBp[buf][n2][tq + 2][0]);  // pairs t+2, t+3
            cq0 = *(const f32x4*)(&sCp[buf][n2][tq][0]);
            cq1 = *(const f32x4*)(&sCp[buf][n2][tq + 2][0]);
        };

        f32x4 dv_p, dxv_p, bq0_p, bq1_p, cq0_p, cq1_p;
        LDQ(0, dv_p, dxv_p, bq0_p, bq1_p, cq0_p, cq1_p);

        float pout[4];
#pragma unroll 4
        for (int tq = 0; tq < 32; tq += 4) {
            const f32x4 dv = dv_p, dxv = dxv_p;
            const f32x4 bq0 = bq0_p, bq1 = bq1_p, cq0 = cq0_p, cq1 = cq1_p;
            // prefetch next 4-t group (wraps harmlessly on last iteration)
            LDQ((tq + 4) & 31, dv_p, dxv_p, bq0_p, bq1_p, cq0_p, cq1_p);

#define SSTEP(DC, DXC, BT, CT, TI)                                   \
            {                                                        \
                f32x2 arg = a01 * (DC);                              \
                f32x2 ee; ee.x = EXP2(arg.x); ee.y = EXP2(arg.y);    \
                h01 = ee * h01 + (BT) * (DXC);                       \
                f32x2 pp = h01 * (CT);                               \
                float p = pp.x + pp.y;                               \
                p = dpp_add<DPP_XOR1>(p);                            \
                p = dpp_add<DPP_XOR2>(p);                            \
                p = dpp_add<DPP_HMIR>(p);                            \
                pout[TI] = p;                                        \
            }
            SSTEP(dv.x, dxv.x, bq0.xy, cq0.xy, 0)
            SSTEP(dv.y, dxv.y, bq0.zw, cq0.zw, 1)
            SSTEP(dv.z, dxv.z, bq1.xy, cq1.xy, 2)
            SSTEP(dv.w, dxv.w, bq1.zw, cq1.zw, 3)
#undef SSTEP

            if (n2 == 0) {
                sy[buf][tq + 0][el] = pout[0];
                sy[buf][tq + 1][el] = pout[1];
                sy[buf][tq + 2][el] = pout[2];
                sy[buf][tq + 3][el] = pout[3];
            }
        }

        if (c > 0) flush(c - 1);

        if (c < 15) {
            write_lds((c + 1) & 1);
            rx_f = rx_c; rz_f = rz_c;
            rx_c = rx;   rz_c = rz;
        } else {
            rx_f = rx_c; rz_f = rz_c;
        }
    }
    __syncthreads();
    flush(15);
}

// ---------------------------------------------------------------------------
// Workspace layout (bytes)
// ---------------------------------------------------------------------------
static const size_t TT = 2048;  // B_SZ * L
static const size_t OFF_XZ16  = 0;                          // 16MB
static const size_t OFF_XC16  = OFF_XZ16  + TT*4096*2;      // 16MB
static const size_t OFF_DBC16 = OFF_XC16  + 2*TT*2048*2;    // .75MB
static const size_t OFF_DELTA = OFF_DBC16 + 2*TT*96*2;      // 16MB (reused: g4 partials kz 0,1)
static const size_t OFF_YF    = OFF_DELTA + 2*TT*2048*2;    // 8MB
static const size_t OFF_YB    = OFF_YF    + TT*2048*2;      // 8MB
static const size_t OFF_YC16  = OFF_YB    + TT*2048*2;      // 8MB (unused)
static const size_t OFF_X16   = OFF_YC16  + TT*2048*2;      // 4MB
static const size_t OFF_WIN16 = OFF_X16   + TT*1024*2;      // 8MB
static const size_t OFF_WX16  = OFF_WIN16 + 4096*1024*2;    // .75MB
static const size_t OFF_WDT16 = OFF_WX16  + 2*96*2048*2;    // .5MB
static const size_t OFF_WOUT16= OFF_WDT16 + 2*2048*64*2;    // 4MB
static const size_t OFF_PART  = OFF_WOUT16+ 1024*2048*2;    // 6.3MB (4 slices)

extern "C" void kernel_launch(void* const* d_in, const int* in_sizes, int n_in,
                              void* d_out, int out_size, void* d_ws, size_t ws_size,
                              hipStream_t stream) {
    const float* x       = (const float*)d_in[0];
    const float* W_in    = (const float*)d_in[1];
    const float* conv_w  = (const float*)d_in[2];
    const float* conv_b  = (const float*)d_in[3];
    const float* Wx      = (const float*)d_in[4];
    const float* Wdt     = (const float*)d_in[5];
    const float* b_dt    = (const float*)d_in[6];
    const float* A_log   = (const float*)d_in[7];
    const float* Dp      = (const float*)d_in[8];
    const float* conv_w_b= (const float*)d_in[9];
    const float* conv_b_b= (const float*)d_in[10];
    const float* Wx_b    = (const float*)d_in[11];
    const float* Wdt_b   = (const float*)d_in[12];
    const float* b_dt_b  = (const float*)d_in[13];
    const float* A_log_b = (const float*)d_in[14];
    const float* Dp_b    = (const float*)d_in[15];
    const float* W_out   = (const float*)d_in[16];
    float* out = (float*)d_out;

    char* ws = (char*)d_ws;
    ushort_t* xz16  = (ushort_t*)(ws + OFF_XZ16);
    ushort_t* xc16  = (ushort_t*)(ws + OFF_XC16);
    ushort_t* dbc16 = (ushort_t*)(ws + OFF_DBC16);
    ushort_t* delta = (ushort_t*)(ws + OFF_DELTA);
    ushort_t* yf    = (ushort_t*)(ws + OFF_YF);
    ushort_t* yb    = (ushort_t*)(ws + OFF_YB);
    ushort_t* x16   = (ushort_t*)(ws + OFF_X16);
    ushort_t* win16 = (ushort_t*)(ws + OFF_WIN16);
    ushort_t* wx16  = (ushort_t*)(ws + OFF_WX16);
    ushort_t* wdt16 = (ushort_t*)(ws + OFF_WDT16);
    ushort_t* wout16= (ushort_t*)(ws + OFF_WOUT16);
    float*    part  = (float*)(ws + OFF_PART);
    float*    p01   = (float*)(ws + OFF_DELTA);   // delta dead after scan (16MB)

    dim3 blk(256);

    CastArgs ca;
    const int n4s[7] = {524288, 1048576, 49152, 49152, 32768, 32768, 524288};
    ca.seg[0] = { (const float4*)x,     (ushort4*)x16 };
    ca.seg[1] = { (const float4*)W_in,  (ushort4*)win16 };
    ca.seg[2] = { (const float4*)Wx,    (ushort4*)wx16 };
    ca.seg[3] = { (const float4*)Wx_b,  (ushort4*)(wx16 + 96 * 2048) };
    ca.seg[4] = { (const float4*)Wdt,   (ushort4*)wdt16 };
    ca.seg[5] = { (const float4*)Wdt_b, (ushort4*)(wdt16 + 2048 * 64) };
    ca.seg[6] = { (const float4*)W_out, (ushort4*)wout16 };
    ca.start[0] = 0;
    for (int i = 0; i < 7; i++) ca.start[i + 1] = ca.start[i] + n4s[i];
    cast_multi<<<(ca.start[7] + 255) / 256, blk, 0, stream>>>(ca);

    gemm_g1<<<dim3(32, 32), blk, 0, stream>>>(x16, 1024, win16, 1024, xz16, 4096, 1024);

    conv_silu_kernel<<<4096, blk, 0, stream>>>(xz16, conv_w, conv_b, conv_w_b, conv_b_b, xc16);

    gemm_g2<<<dim3(4, 32, 2), blk, 0, stream>>>(xc16, wx16, part);
    reduce_dbc<<<384, blk, 0, stream>>>((const float4*)part, (ushort4*)dbc16);

    gemm_g3<<<dim3(16, 32, 2), blk, 0, stream>>>(dbc16, wdt16, delta, b_dt, b_dt_b);

    scan_kernel<<<512, blk, 0, stream>>>(delta, xc16, dbc16, xz16, A_log, A_log_b, Dp, Dp_b, yf, yb);

    gemm_g4<<<dim3(8, 32, 2), blk, 0, stream>>>(yf, yb, wout16, 2048, p01);
    reduce_g4<<<2048, blk, 0, stream>>>((const float4*)p01, (float4*)out);
}

// Round 8
// 256.647 us; speedup vs baseline: 1.0152x; 1.0152x over previous
//
#include <hip/hip_runtime.h>
#include <hip/hip_bf16.h>
#include <stdint.h>

typedef unsigned short ushort_t;
typedef __attribute__((ext_vector_type(8))) short short8;
typedef __attribute__((ext_vector_type(4))) float f32x4;
typedef __attribute__((ext_vector_type(2))) float f32x2;

__device__ __forceinline__ float b2f(ushort_t u) {
    union { uint32_t i; float f; } v; v.i = ((uint32_t)u) << 16; return v.f;
}
__device__ __forceinline__ ushort_t f2b(float f) {
    union { float f; uint32_t i; } v; v.f = f;
    uint32_t r = v.i + 0x7fff + ((v.i >> 16) & 1);
    return (ushort_t)(r >> 16);
}

#if __has_builtin(__builtin_amdgcn_exp2f)
#define EXP2(x) __builtin_amdgcn_exp2f(x)
#else
#define EXP2(x) __expf((x) * 0.69314718056f)
#endif

// async global->LDS, 16B per lane; lds base must be wave-uniform
__device__ __forceinline__ void ll16(const ushort_t* g, ushort_t* l) {
    __builtin_amdgcn_global_load_lds(
        (const __attribute__((address_space(1))) uint32_t*)g,
        (__attribute__((address_space(3))) uint32_t*)l, 16, 0, 0);
}

// DPP cross-lane add (VALU pipe)
template <int CTRL>
__device__ __forceinline__ float dpp_add(float p) {
    int v = __builtin_amdgcn_update_dpp(0, __float_as_int(p), CTRL, 0xF, 0xF, true);
    return p + __int_as_float(v);
}
#define DPP_XOR1 0xB1
#define DPP_XOR2 0x4E
#define DPP_HMIR 0x141

// ---------------------------------------------------------------------------
// Coalesced epilogues: wave's 16x64 output group via private LDS scratch.
// ---------------------------------------------------------------------------
__device__ __forceinline__ void epi_wave_f32(
    float* sw, const f32x4* accg, float* dst0, int ldc, int lane)
{
    const int quad = lane >> 4, lr = lane & 15;
#pragma unroll
    for (int j = 0; j < 4; j++)
#pragma unroll
        for (int r = 0; r < 4; r++)
            sw[(quad * 4 + r) * 64 + j * 16 + lr] = accg[j][r];
    __asm__ volatile("s_waitcnt lgkmcnt(0)" ::: "memory");
#pragma unroll
    for (int t = 0; t < 4; t++) {
        int row = t * 4 + quad;
        float4 v = *(const float4*)(&sw[row * 64 + lr * 4]);
        *(float4*)(dst0 + (size_t)row * ldc + lr * 4) = v;
    }
}

__device__ __forceinline__ void epi_wave_b16(
    float* sw, const f32x4* accg, ushort_t* dst0, int ldc, int lane)
{
    const int quad = lane >> 4, lr = lane & 15;
#pragma unroll
    for (int j = 0; j < 4; j++)
#pragma unroll
        for (int r = 0; r < 4; r++)
            sw[(quad * 4 + r) * 64 + j * 16 + lr] = accg[j][r];
    __asm__ volatile("s_waitcnt lgkmcnt(0)" ::: "memory");
#pragma unroll
    for (int t = 0; t < 4; t++) {
        int row = t * 4 + quad;
        float4 v = *(const float4*)(&sw[row * 64 + lr * 4]);
        ushort4 o; o.x = f2b(v.x); o.y = f2b(v.y); o.z = f2b(v.z); o.w = f2b(v.w);
        *(ushort4*)(dst0 + (size_t)row * ldc + lr * 4) = o;
    }
}

// ---------------------------------------------------------------------------
// Fused multi-tensor fp32 -> bf16 cast (7 segments, 1 launch)
// ---------------------------------------------------------------------------
struct CastSeg { const float4* src; ushort4* dst; };
struct CastArgs { CastSeg seg[7]; int start[8]; };

__global__ __launch_bounds__(256) void cast_multi(CastArgs a)
{
    int g = blockIdx.x * 256 + threadIdx.x;
    if (g >= a.start[7]) return;
    int s = 0;
#pragma unroll
    for (int i = 1; i < 7; i++) s += (g >= a.start[i]);
    int i = g - a.start[s];
    float4 v = a.seg[s].src[i];
    ushort4 o;
    o.x = f2b(v.x); o.y = f2b(v.y); o.z = f2b(v.z); o.w = f2b(v.w);
    a.seg[s].dst[i] = o;
}

#define BK 32

// ---------------------------------------------------------------------------
// G1 v13: BM=64 tiles -> 1024 blocks, XCD-swizzled, double-buffered.
// ---------------------------------------------------------------------------
__global__ __launch_bounds__(256, 4) void gemm_g1(
    const ushort_t* __restrict__ A, int lda,
    const ushort_t* __restrict__ B, int ldb,
    ushort_t* __restrict__ Cout, int ldc, int Kd)
{
    __shared__ ushort_t As[2][64 * BK];
    __shared__ ushort_t Bs[2][128 * BK];
    __shared__ float sepi[4][1024];

    // XCD swizzle: nwg = 32*32 = 1024, q = 128
    const int flat = blockIdx.y * 32 + blockIdx.x;
    const int swz  = (flat & 7) * 128 + (flat >> 3);
    const int n0   = (swz & 31) * 128;
    const int m0   = (swz >> 5) * 64;

    const int tid  = threadIdx.x;
    const int wv   = tid >> 6;
    const int lane = tid & 63;
    const int wm   = (wv >> 1) * 32;
    const int wn   = (wv & 1) * 64;
    const int lr   = lane & 15;
    const int quad = lane >> 4;

    f32x4 acc[2][4];
#pragma unroll
    for (int i = 0; i < 2; i++)
#pragma unroll
        for (int j = 0; j < 4; j++) acc[i][j] = f32x4{0.f, 0.f, 0.f, 0.f};

    const int srA = wv * 16 + (lane >> 2);
    const int srB = wv * 32 + (lane >> 2);
    const int sc  = (lane & 3) * 8;

    auto stage = [&](int bf_, int k0) {
        ll16(A + (size_t)(m0 + srA) * lda + k0 + sc,      &As[bf_][wv * 512]);
        ll16(B + (size_t)(n0 + srB) * ldb + k0 + sc,      &Bs[bf_][wv * 1024]);
        ll16(B + (size_t)(n0 + srB + 16) * ldb + k0 + sc, &Bs[bf_][wv * 1024 + 512]);
    };

    const int nk = Kd / BK;
    stage(0, 0);
    __syncthreads();

    for (int t = 0; t < nk; ++t) {
        const int buf = t & 1;
        if (t + 1 < nk) stage(buf ^ 1, (t + 1) * BK);

        short8 af[2], bfr[4];
#pragma unroll
        for (int i = 0; i < 2; i++)
            af[i] = *(const short8*)(&As[buf][(wm + i * 16 + lr) * BK + quad * 8]);
#pragma unroll
        for (int j = 0; j < 4; j++)
            bfr[j] = *(const short8*)(&Bs[buf][(wn + j * 16 + lr) * BK + quad * 8]);
#pragma unroll
        for (int i = 0; i < 2; i++)
#pragma unroll
            for (int j = 0; j < 4; j++)
                acc[i][j] = __builtin_amdgcn_mfma_f32_16x16x32_bf16(af[i], bfr[j], acc[i][j], 0, 0, 0);
        __syncthreads();
    }

#pragma unroll
    for (int g = 0; g < 2; g++)
        epi_wave_b16(sepi[wv], acc[g],
                     Cout + (size_t)(m0 + wm + g * 16) * ldc + n0 + wn, ldc, lane);
}

// ---------------------------------------------------------------------------
// G4 v13 (R6 best): combine fused, split-K=4 (1024 blocks = 4/CU), partials
// in two workspace spans (kz 0,1 -> p01; kz 2,3 -> p23), XCD-swizzled.
// ---------------------------------------------------------------------------
__global__ __launch_bounds__(256, 4) void gemm_g4(
    const ushort_t* __restrict__ yfp, const ushort_t* __restrict__ ybp,
    const ushort_t* __restrict__ B, int ldb,
    float* __restrict__ p01, float* __restrict__ p23)
{
    __shared__ ushort_t As[2][64 * BK];
    __shared__ ushort_t Bs[2][128 * BK];
    __shared__ float sepi[4][1024];

    // XCD swizzle: nwg = 8*32*4 = 1024, q = 128
    const int flat = (blockIdx.z * 32 + blockIdx.y) * 8 + blockIdx.x;
    const int swz  = (flat & 7) * 128 + (flat >> 3);
    const int n0   = (swz & 7) * 128;
    const int m0   = ((swz >> 3) & 31) * 64;
    const int kz   = swz >> 8;

    const int tid  = threadIdx.x;
    const int kbase = kz * 512;
    const int wv   = tid >> 6;
    const int lane = tid & 63;
    const int wm   = (wv >> 1) * 32;
    const int wn   = (wv & 1) * 64;
    const int lr   = lane & 15;
    const int quad = lane >> 4;

    f32x4 acc[2][4];
#pragma unroll
    for (int i = 0; i < 2; i++)
#pragma unroll
        for (int j = 0; j < 4; j++) acc[i][j] = f32x4{0.f, 0.f, 0.f, 0.f};

    const int srA = wv * 16 + (lane >> 2);
    const int srB = wv * 32 + (lane >> 2);
    const int sc  = (lane & 3) * 8;

    // A row -> forward/backward y rows (combine fusion)
    const int arow = m0 + srA;
    const int t_   = arow & 511;
    const size_t yf_off = (size_t)arow * 2048;
    const size_t yb_off = (size_t)(arow - t_ + 511 - t_) * 2048;

    uint4 ra, rb;
    auto loadA = [&](int k0) {
        ra = *(const uint4*)(yfp + yf_off + kbase + k0 + sc);
        rb = *(const uint4*)(ybp + yb_off + kbase + k0 + sc);
    };
    auto writeA = [&](int bf_) {
        const uint32_t pa[4] = { ra.x, ra.y, ra.z, ra.w };
        const uint32_t pb[4] = { rb.x, rb.y, rb.z, rb.w };
        uint32_t w[4];
#pragma unroll
        for (int k = 0; k < 4; k++) {
            float a0 = b2f((ushort_t)(pa[k] & 0xffff));
            float a1 = b2f((ushort_t)(pa[k] >> 16));
            float c0 = b2f((ushort_t)(pb[k] & 0xffff));
            float c1 = b2f((ushort_t)(pb[k] >> 16));
            w[k] = (uint32_t)f2b(0.5f * (a0 + c0)) |
                   ((uint32_t)f2b(0.5f * (a1 + c1)) << 16);
        }
        *(uint4*)(&As[bf_][wv * 512 + (lane >> 2) * 32 + (lane & 3) * 8]) =
            make_uint4(w[0], w[1], w[2], w[3]);
    };
    auto stageB = [&](int bf_, int k0) {
        ll16(B + (size_t)(n0 + srB) * ldb + kbase + k0 + sc,      &Bs[bf_][wv * 1024]);
        ll16(B + (size_t)(n0 + srB + 16) * ldb + kbase + k0 + sc, &Bs[bf_][wv * 1024 + 512]);
    };

    const int nk = 512 / BK;
    loadA(0);
    stageB(0, 0);
    writeA(0);
    __syncthreads();

    for (int t = 0; t < nk; ++t) {
        const int buf = t & 1;
        if (t + 1 < nk) {
            loadA((t + 1) * BK);              // issue early (hides under MFMA)
            stageB(buf ^ 1, (t + 1) * BK);
        }

        short8 af[2], bfr[4];
#pragma unroll
        for (int i = 0; i < 2; i++)
            af[i] = *(const short8*)(&As[buf][(wm + i * 16 + lr) * BK + quad * 8]);
#pragma unroll
        for (int j = 0; j < 4; j++)
            bfr[j] = *(const short8*)(&Bs[buf][(wn + j * 16 + lr) * BK + quad * 8]);
#pragma unroll
        for (int i = 0; i < 2; i++)
#pragma unroll
            for (int j = 0; j < 4; j++)
                acc[i][j] = __builtin_amdgcn_mfma_f32_16x16x32_bf16(af[i], bfr[j], acc[i][j], 0, 0, 0);

        if (t + 1 < nk) writeA(buf ^ 1);      // write late (after compute)
        __syncthreads();
    }

    float* base = (kz < 2) ? p01 : p23;
    float* Cout = base + (size_t)(kz & 1) * 2048 * 1024;
#pragma unroll
    for (int g = 0; g < 2; g++)
        epi_wave_f32(sepi[wv], acc[g],
                     Cout + (size_t)(m0 + wm + g * 16) * 1024 + n0 + wn, 1024, lane);
}

__global__ __launch_bounds__(256) void reduce_g4(
    const float4* __restrict__ p01, const float4* __restrict__ p23,
    float4* __restrict__ out)
{
    int g = blockIdx.x * 256 + threadIdx.x;   // 524288 total
    const int S = 2048 * 1024 / 4;
    float4 a = p01[g], b = p01[g + S], c = p23[g], d = p23[g + S];
    float4 o;
    o.x = (a.x + b.x) + (c.x + d.x);
    o.y = (a.y + b.y) + (c.y + d.y);
    o.z = (a.z + b.z) + (c.z + d.z);
    o.w = (a.w + b.w) + (c.w + d.w);
    out[g] = o;
}

// ---------------------------------------------------------------------------
// G2 v13 (R6 best): BM=64 -> grid (SK=8, M/64=32, br=2) = 512 blocks = 2/CU.
// ---------------------------------------------------------------------------
__global__ __launch_bounds__(256, 4) void gemm_g2(
    const ushort_t* __restrict__ xc, const ushort_t* __restrict__ wx,
    float* __restrict__ part)
{
    __shared__ ushort_t As[2][64 * BK];
    __shared__ ushort_t Bs[2][128 * BK];
    __shared__ float sepi[4][1024];

    // XCD swizzle: nwg = 8*32*2 = 512, q = 64
    const int flat = (blockIdx.z * 32 + blockIdx.y) * 8 + blockIdx.x;
    const int swz  = (flat & 7) * 64 + (flat >> 3);
    const int sk   = swz & 7;
    const int mb   = (swz >> 3) & 31;
    const int br   = swz >> 8;

    const ushort_t* A = xc + (size_t)br * 2048 * 2048;
    const ushort_t* B = wx + (size_t)br * 96 * 2048;
    float* C = part + (size_t)(sk * 2 + br) * 2048 * 96;
    const int m0 = mb * 64;
    const int kb = sk * 256;

    const int tid  = threadIdx.x;
    const int wv   = tid >> 6;
    const int lane = tid & 63;
    const int wm   = (wv >> 1) * 32;
    const int wn   = (wv & 1) * 64;
    const int lr   = lane & 15;
    const int quad = lane >> 4;

    f32x4 acc[2][4];
#pragma unroll
    for (int i = 0; i < 2; i++)
#pragma unroll
        for (int j = 0; j < 4; j++) acc[i][j] = f32x4{0.f, 0.f, 0.f, 0.f};

    const int srA = wv * 16 + (lane >> 2);
    const int srB = wv * 32 + (lane >> 2);
    const int sc  = (lane & 3) * 8;

    auto stage = [&](int bf_, int k0) {
        ll16(A + (size_t)(m0 + srA) * 2048 + k0 + sc,      &As[bf_][wv * 512]);
        ll16(B + (size_t)(srB) * 2048 + k0 + sc,           &Bs[bf_][wv * 1024]);
        ll16(B + (size_t)(srB + 16) * 2048 + k0 + sc,      &Bs[bf_][wv * 1024 + 512]);
    };

    stage(0, kb);
    __syncthreads();

    for (int t = 0; t < 8; ++t) {
        const int buf = t & 1;
        if (t + 1 < 8) stage(buf ^ 1, kb + (t + 1) * BK);

        short8 af[2], bfr[4];
#pragma unroll
        for (int i = 0; i < 2; i++)
            af[i] = *(const short8*)(&As[buf][(wm + i * 16 + lr) * BK + quad * 8]);
#pragma unroll
        for (int j = 0; j < 4; j++)
            bfr[j] = *(const short8*)(&Bs[buf][(wn + j * 16 + lr) * BK + quad * 8]);
#pragma unroll
        for (int i = 0; i < 2; i++)
#pragma unroll
            for (int j = 0; j < 4; j++)
                acc[i][j] = __builtin_amdgcn_mfma_f32_16x16x32_bf16(af[i], bfr[j], acc[i][j], 0, 0, 0);
        __syncthreads();
    }

    float* sw = sepi[wv];
#pragma unroll
    for (int g = 0; g < 2; g++) {
#pragma unroll
        for (int j = 0; j < 4; j++)
#pragma unroll
            for (int r = 0; r < 4; r++)
                sw[(quad * 4 + r) * 64 + j * 16 + lr] = acc[g][j][r];
        __asm__ volatile("s_waitcnt lgkmcnt(0)" ::: "memory");
        int col = wn + lr * 4;
#pragma unroll
        for (int t = 0; t < 4; t++) {
            int row = t * 4 + quad;
            if (col < 96) {
                float4 v = *(const float4*)(&sw[row * 64 + lr * 4]);
                *(float4*)(C + (size_t)(m0 + wm + g * 16 + row) * 96 + col) = v;
            }
        }
    }
}

__global__ __launch_bounds__(256) void reduce_dbc(
    const float4* __restrict__ part, ushort4* __restrict__ dbc16)
{
    int g = blockIdx.x * 256 + threadIdx.x;   // 98304 total
    const int S = 2 * 2048 * 96 / 4;
    float4 r = part[g];
#pragma unroll
    for (int i = 1; i < 8; i++) {
        float4 p = part[g + i * S];
        r.x += p.x; r.y += p.y; r.z += p.z; r.w += p.w;
    }
    ushort4 o; o.x = f2b(r.x); o.y = f2b(r.y); o.z = f2b(r.z); o.w = f2b(r.w);
    dbc16[g] = o;
}

// ---------------------------------------------------------------------------
// G3 v13: BM=64 -> grid (16, 32, 2) = 1024 blocks, XCD-swizzled.
// ---------------------------------------------------------------------------
__global__ __launch_bounds__(256, 4) void gemm_g3(
    const ushort_t* __restrict__ dbc16, const ushort_t* __restrict__ wdt,
    ushort_t* __restrict__ delta,
    const float* __restrict__ bdt_f, const float* __restrict__ bdt_b)
{
    __shared__ ushort_t As[2][64 * BK];
    __shared__ ushort_t Bs[2][128 * BK];
    __shared__ float sepi[4][1024];

    // XCD swizzle: nwg = 16*32*2 = 1024, q = 128
    const int flat = (blockIdx.z * 32 + blockIdx.y) * 16 + blockIdx.x;
    const int swz  = (flat & 7) * 128 + (flat >> 3);
    const int n0   = (swz & 15) * 128;
    const int m0   = ((swz >> 4) & 31) * 64;
    const int br   = swz >> 9;

    const ushort_t* A = dbc16 + (size_t)br * 2048 * 96;
    const ushort_t* B = wdt + (size_t)br * 2048 * 64;
    ushort_t* C = delta + (size_t)br * 2048 * 2048;
    const float* bias = br ? bdt_b : bdt_f;

    const int tid  = threadIdx.x;
    const int wv   = tid >> 6;
    const int lane = tid & 63;
    const int wm   = (wv >> 1) * 32;
    const int wn   = (wv & 1) * 64;
    const int lr   = lane & 15;
    const int quad = lane >> 4;

    f32x4 acc[2][4];
#pragma unroll
    for (int i = 0; i < 2; i++)
#pragma unroll
        for (int j = 0; j < 4; j++) acc[i][j] = f32x4{0.f, 0.f, 0.f, 0.f};

    const int srA = wv * 16 + (lane >> 2);
    const int srB = wv * 32 + (lane >> 2);
    const int sc  = (lane & 3) * 8;

    auto stage = [&](int bf_, int k0) {
        ll16(A + (size_t)(m0 + srA) * 96 + k0 + sc,       &As[bf_][wv * 512]);
        ll16(B + (size_t)(n0 + srB) * 64 + k0 + sc,       &Bs[bf_][wv * 1024]);
        ll16(B + (size_t)(n0 + srB + 16) * 64 + k0 + sc,  &Bs[bf_][wv * 1024 + 512]);
    };

    stage(0, 0);
    __syncthreads();

    for (int t = 0; t < 2; ++t) {
        const int buf = t & 1;
        if (t + 1 < 2) stage(buf ^ 1, (t + 1) * BK);

        short8 af[2], bfr[4];
#pragma unroll
        for (int i = 0; i < 2; i++)
            af[i] = *(const short8*)(&As[buf][(wm + i * 16 + lr) * BK + quad * 8]);
#pragma unroll
        for (int j = 0; j < 4; j++)
            bfr[j] = *(const short8*)(&Bs[buf][(wn + j * 16 + lr) * BK + quad * 8]);
#pragma unroll
        for (int i = 0; i < 2; i++)
#pragma unroll
            for (int j = 0; j < 4; j++)
                acc[i][j] = __builtin_amdgcn_mfma_f32_16x16x32_bf16(af[i], bfr[j], acc[i][j], 0, 0, 0);
        __syncthreads();
    }

    float bn[4];
#pragma unroll
    for (int j = 0; j < 4; j++) bn[j] = bias[n0 + wn + j * 16 + lr];
#pragma unroll
    for (int g = 0; g < 2; g++)
#pragma unroll
        for (int j = 0; j < 4; j++)
#pragma unroll
            for (int r = 0; r < 4; r++) {
                float x = acc[g][j][r] + bn[j];
                float sp = fmaxf(x, 0.f) + __logf(1.f + __expf(-fabsf(x)));
                acc[g][j][r] = sp;
            }

#pragma unroll
    for (int g = 0; g < 2; g++)
        epi_wave_b16(sepi[wv], acc[g],
                     C + (size_t)(m0 + wm + g * 16) * 2048 + n0 + wn, 2048, lane);
}

// ---------------------------------------------------------------------------
// Causal depthwise conv (K=4) + bias + silu, v2 (R6 best): 8 elems/thread.
// ---------------------------------------------------------------------------
__global__ __launch_bounds__(256) void conv_silu_kernel(
    const ushort_t* __restrict__ xz,
    const float* __restrict__ w_f, const float* __restrict__ cb_f,
    const float* __restrict__ w_b, const float* __restrict__ cb_b,
    ushort_t* __restrict__ xc16)
{
    int g = blockIdx.x * 256 + threadIdx.x;   // 1,048,576 total
    int e0 = (g & 255) * 8;
    int t  = (g >> 8) & 511;
    int b  = (g >> 17) & 3;
    int br = g >> 19;

    const float* w  = br ? w_b  : w_f;
    const float* cb = br ? cb_b : cb_f;

    // taps (zeroed when t-3+k < 0; b2f(0) == 0.0f)
    uint32_t tv[4][4];
#pragma unroll
    for (int k = 0; k < 4; k++) {
        int tp = t - 3 + k;
        if (tp >= 0) {                          // wave-uniform (t const per wave)
            int row = br ? (511 - tp) : tp;
            uint4 xv = *(const uint4*)(xz + ((size_t)(b * 512 + row)) * 4096 + e0);
            tv[k][0] = xv.x; tv[k][1] = xv.y; tv[k][2] = xv.z; tv[k][3] = xv.w;
        } else {
            tv[k][0] = 0; tv[k][1] = 0; tv[k][2] = 0; tv[k][3] = 0;
        }
    }

    float4 cbv0 = *(const float4*)(cb + e0);
    float4 cbv1 = *(const float4*)(cb + e0 + 4);
    const float cbs[8] = { cbv0.x, cbv0.y, cbv0.z, cbv0.w,
                           cbv1.x, cbv1.y, cbv1.z, cbv1.w };

    uint32_t op[4];
#pragma unroll
    for (int q = 0; q < 4; q++) {
        float4 wA = *(const float4*)(w + (e0 + 2 * q) * 4);
        float4 wB = *(const float4*)(w + (e0 + 2 * q + 1) * 4);
        float a0 = cbs[2 * q]
                 + wA.x * b2f((ushort_t)(tv[0][q] & 0xffff))
                 + wA.y * b2f((ushort_t)(tv[1][q] & 0xffff))
                 + wA.z * b2f((ushort_t)(tv[2][q] & 0xffff))
                 + wA.w * b2f((ushort_t)(tv[3][q] & 0xffff));
        float a1 = cbs[2 * q + 1]
                 + wB.x * b2f((ushort_t)(tv[0][q] >> 16))
                 + wB.y * b2f((ushort_t)(tv[1][q] >> 16))
                 + wB.z * b2f((ushort_t)(tv[2][q] >> 16))
                 + wB.w * b2f((ushort_t)(tv[3][q] >> 16));
        float s0 = a0 / (1.f + __expf(-a0));
        float s1 = a1 / (1.f + __expf(-a1));
        op[q] = (uint32_t)f2b(s0) | ((uint32_t)f2b(s1) << 16);
    }
    *(uint4*)(xc16 + (size_t)g * 8) = make_uint4(op[0], op[1], op[2], op[3]);
}

// ---------------------------------------------------------------------------
// Selective scan v11: v10 + full unroll of the inner 32-t loop (scheduler
// gets the whole chunk's LDS reads to hoist; sync structure unchanged).
// ---------------------------------------------------------------------------
__global__ __launch_bounds__(256, 4) void scan_kernel(
    const ushort_t* __restrict__ delta,   // [2][B][L][ED] bf16
    const ushort_t* __restrict__ xc,      // [2][B][L][ED] bf16
    const ushort_t* __restrict__ dbc16,   // [2][B][L][96] bf16
    const ushort_t* __restrict__ xz,      // [B][L][4096] bf16 (z half)
    const float* __restrict__ Alog_f, const float* __restrict__ Alog_b,
    const float* __restrict__ Dp_f,   const float* __restrict__ Dp_b,
    ushort_t* __restrict__ yf, ushort_t* __restrict__ yb)
{
    const int blk = blockIdx.x;            // 0..511
    const int eg = blk & 63;
    const int b  = (blk >> 6) & 3;
    const int br = blk >> 8;
    const int e0 = eg * 32;

    const int tid = threadIdx.x;
    const int n2  = tid & 7;               // hot-loop: state index
    const int el  = tid >> 3;              // hot-loop: element 0..31
    const int e   = e0 + el;

    const float* Alog = br ? Alog_b : Alog_f;
    const float* Dpp  = br ? Dp_b   : Dp_f;
    // pre-scaled by log2(e) so dA = exp2(d * A); packed pair (n2, n2+8)
    f32x2 a01;
    a01.x = -__expf(Alog[e * 16 + n2]) * 1.44269504f;
    a01.y = -__expf(Alog[e * 16 + n2 + 8]) * 1.44269504f;

    size_t tb = ((size_t)br * 4 + b) * 512;
    const ushort_t* dlt  = delta + tb * 2048;
    const ushort_t* xcb  = xc    + tb * 2048;
    const ushort_t* dbcb = dbc16 + tb * 96;
    ushort_t* y = (br ? yb : yf) + (size_t)b * 512 * 2048;

    __shared__ float sd [2][32][36];       // d[e][t^key(e)]
    __shared__ float sdx[2][32][36];       // (d*x)[e][t^key(e)]
    __shared__ float sBp[2][8][34][2];     // {B[n],B[n+8]}[t] packed pairs
    __shared__ float sCp[2][8][34][2];     // {C[n],C[n+8]}[t]
    __shared__ float sy [2][32][33];       // y[t][e], ping-pong

    const int stt = tid >> 3;              // staging: t within chunk 0..31
    const int seg = tid & 7;               // staging: 4-elem column group
    const int sg4 = seg * 4;
    const int sdk = (seg & 3) * 8;         // store-side xor key (rows seg*4..+3)

    float4 rD = *(const float4*)(Dpp + e0 + sg4);

    uint2 rdx, rx, rbc, rz;
    uint2 rx_c, rx_f, rz_c, rz_f;

    auto load_regs = [&](int c) {
        int row = c * 32 + stt;
        rdx = *(const uint2*)(dlt + (size_t)row * 2048 + e0 + sg4);
        rx  = *(const uint2*)(xcb + (size_t)row * 2048 + e0 + sg4);
        rbc = *(const uint2*)(dbcb + (size_t)row * 96 + 64 + sg4);
        int orow = br ? (511 - row) : row;
        rz  = *(const uint2*)(xz + ((size_t)(b * 512 + orow)) * 4096 + 2048 + e0 + sg4);
    };
    auto write_lds = [&](int buf) {
        const uint32_t dw[2] = { rdx.x, rdx.y };
        const uint32_t xw[2] = { rx.x, rx.y };
        const int col = stt ^ sdk;
#pragma unroll
        for (int k = 0; k < 2; k++) {
            float d0 = b2f((ushort_t)(dw[k] & 0xffff));
            float d1 = b2f((ushort_t)(dw[k] >> 16));
            float x0 = b2f((ushort_t)(xw[k] & 0xffff));
            float x1 = b2f((ushort_t)(xw[k] >> 16));
            sd [buf][sg4 + 2 * k][col]     = d0;
            sd [buf][sg4 + 2 * k + 1][col] = d1;
            sdx[buf][sg4 + 2 * k][col]     = d0 * x0;
            sdx[buf][sg4 + 2 * k + 1][col] = d1 * x1;
        }
        // B/C interleaved pairs: seg 0..3 -> B n=(seg*4..+3), seg 4..7 -> C
        float* arr = (seg < 4) ? &sBp[buf][0][0][0] : &sCp[buf][0][0][0];
        const int nb = (seg & 3) * 4;
        const uint32_t bw[2] = { rbc.x, rbc.y };
#pragma unroll
        for (int k = 0; k < 2; k++) {
            int na = nb + 2 * k, nbd = nb + 2 * k + 1;
            arr[(na  & 7) * 68 + stt * 2 + (na  >> 3)] = b2f((ushort_t)(bw[k] & 0xffff));
            arr[(nbd & 7) * 68 + stt * 2 + (nbd >> 3)] = b2f((ushort_t)(bw[k] >> 16));
        }
    };
    auto flush = [&](int cm1) {
        const int bufm1 = cm1 & 1;
        int row = cm1 * 32 + stt;
        const uint32_t zw[2] = { rz_f.x, rz_f.y };
        float zv[4];
#pragma unroll
        for (int k = 0; k < 2; k++) {
            zv[2 * k]     = b2f((ushort_t)(zw[k] & 0xffff));
            zv[2 * k + 1] = b2f((ushort_t)(zw[k] >> 16));
        }
        float pv[4];
#pragma unroll
        for (int k = 0; k < 4; k++) pv[k] = sy[bufm1][stt][sg4 + k];
        const uint32_t xw[2] = { rx_f.x, rx_f.y };
        float xvv[4];
#pragma unroll
        for (int k = 0; k < 2; k++) {
            xvv[2 * k]     = b2f((ushort_t)(xw[k] & 0xffff));
            xvv[2 * k + 1] = b2f((ushort_t)(xw[k] >> 16));
        }
        const float Dv[4] = { rD.x, rD.y, rD.z, rD.w };
        uint32_t op[2];
#pragma unroll
        for (int k = 0; k < 2; k++) {
            float ga = (pv[2 * k]     + Dv[2 * k]     * xvv[2 * k])     *
                       (zv[2 * k]     / (1.f + __expf(-zv[2 * k])));
            float gb = (pv[2 * k + 1] + Dv[2 * k + 1] * xvv[2 * k + 1]) *
                       (zv[2 * k + 1] / (1.f + __expf(-zv[2 * k + 1])));
            op[k] = (uint32_t)f2b(ga) | ((uint32_t)f2b(gb) << 16);
        }
        *(uint2*)(y + (size_t)row * 2048 + e0 + sg4) = make_uint2(op[0], op[1]);
    };

    f32x2 h01 = f32x2{0.f, 0.f};
    const int elk = ((el >> 2) & 3) * 8;   // read-side xor key (matches sdk)

    load_regs(0);
    write_lds(0);
    rx_c = rx; rz_c = rz;

    for (int c = 0; c < 16; ++c) {
        if (c < 15) load_regs(c + 1);
        __syncthreads();
        const int buf = c & 1;

        auto LDQ = [&](int tq, f32x4& dv, f32x4& dxv, f32x4& bq0, f32x4& bq1,
                       f32x4& cq0, f32x4& cq1) {
            const int tc = tq ^ elk;
            dv  = *(const f32x4*)(&sd [buf][el][tc]);
            dxv = *(const f32x4*)(&sdx[buf][el][tc]);
            bq0 = *(const f32x4*)(&sBp[buf][n2][tq][0]);      // pairs t, t+1
            bq1 = *(const f32x4*)(&sBp[buf][n2][tq + 2][0]);  // pairs t+2, t+3
            cq0 = *(const f32x4*)(&sCp[buf][n2][tq][0]);
            cq1 = *(const f32x4*)(&sCp[buf][n2][tq + 2][0]);
        };

        f32x4 dv_p, dxv_p, bq0_p, bq1_p, cq0_p, cq1_p;
        LDQ(0, dv_p, dxv_p, bq0_p, bq1_p, cq0_p, cq1_p);

        float pout[4];
#pragma unroll
        for (int tq = 0; tq < 32; tq += 4) {
            const f32x4 dv = dv_p, dxv = dxv_p;
            const f32x4 bq0 = bq0_p, bq1 = bq1_p, cq0 = cq0_p, cq1 = cq1_p;
            // prefetch next 4-t group (wraps harmlessly on last iteration)
            LDQ((tq + 4) & 31, dv_p, dxv_p, bq0_p, bq1_p, cq0_p, cq1_p);

#define SSTEP(DC, DXC, BT, CT, TI)                                   \
            {                                                        \
                f32x2 arg = a01 * (DC);                              \
                f32x2 ee; ee.x = EXP2(arg.x); ee.y = EXP2(arg.y);    \
                h01 = ee * h01 + (BT) * (DXC);                       \
                f32x2 pp = h01 * (CT);                               \
                float p = pp.x + pp.y;                               \
                p = dpp_add<DPP_XOR1>(p);                            \
                p = dpp_add<DPP_XOR2>(p);                            \
                p = dpp_add<DPP_HMIR>(p);                            \
                pout[TI] = p;                                        \
            }
            SSTEP(dv.x, dxv.x, bq0.xy, cq0.xy, 0)
            SSTEP(dv.y, dxv.y, bq0.zw, cq0.zw, 1)
            SSTEP(dv.z, dxv.z, bq1.xy, cq1.xy, 2)
            SSTEP(dv.w, dxv.w, bq1.zw, cq1.zw, 3)
#undef SSTEP

            if (n2 == 0) {
                sy[buf][tq + 0][el] = pout[0];
                sy[buf][tq + 1][el] = pout[1];
                sy[buf][tq + 2][el] = pout[2];
                sy[buf][tq + 3][el] = pout[3];
            }
        }

        if (c > 0) flush(c - 1);

        if (c < 15) {
            write_lds((c + 1) & 1);
            rx_f = rx_c; rz_f = rz_c;
            rx_c = rx;   rz_c = rz;
        } else {
            rx_f = rx_c; rz_f = rz_c;
        }
    }
    __syncthreads();
    flush(15);
}

// ---------------------------------------------------------------------------
// Workspace layout (bytes)
// ---------------------------------------------------------------------------
static const size_t TT = 2048;  // B_SZ * L
static const size_t OFF_XZ16  = 0;                          // 16MB
static const size_t OFF_XC16  = OFF_XZ16  + TT*4096*2;      // 16MB
static const size_t OFF_DBC16 = OFF_XC16  + 2*TT*2048*2;    // .75MB
static const size_t OFF_DELTA = OFF_DBC16 + 2*TT*96*2;      // 16MB (reused: g4 partials kz 0,1)
static const size_t OFF_YF    = OFF_DELTA + 2*TT*2048*2;    // 8MB
static const size_t OFF_YB    = OFF_YF    + TT*2048*2;      // 8MB
static const size_t OFF_YC16  = OFF_YB    + TT*2048*2;      // 8MB (reused: g4 partials kz 2,3 ...)
static const size_t OFF_X16   = OFF_YC16  + TT*2048*2;      // 4MB (... spans into x16/win16, dead by g4)
static const size_t OFF_WIN16 = OFF_X16   + TT*1024*2;      // 8MB
static const size_t OFF_WX16  = OFF_WIN16 + 4096*1024*2;    // .75MB
static const size_t OFF_WDT16 = OFF_WX16  + 2*96*2048*2;    // .5MB
static const size_t OFF_WOUT16= OFF_WDT16 + 2*2048*64*2;    // 4MB
static const size_t OFF_PART  = OFF_WOUT16+ 1024*2048*2;    // 12.6MB

extern "C" void kernel_launch(void* const* d_in, const int* in_sizes, int n_in,
                              void* d_out, int out_size, void* d_ws, size_t ws_size,
                              hipStream_t stream) {
    const float* x       = (const float*)d_in[0];
    const float* W_in    = (const float*)d_in[1];
    const float* conv_w  = (const float*)d_in[2];
    const float* conv_b  = (const float*)d_in[3];
    const float* Wx      = (const float*)d_in[4];
    const float* Wdt     = (const float*)d_in[5];
    const float* b_dt    = (const float*)d_in[6];
    const float* A_log   = (const float*)d_in[7];
    const float* Dp      = (const float*)d_in[8];
    const float* conv_w_b= (const float*)d_in[9];
    const float* conv_b_b= (const float*)d_in[10];
    const float* Wx_b    = (const float*)d_in[11];
    const float* Wdt_b   = (const float*)d_in[12];
    const float* b_dt_b  = (const float*)d_in[13];
    const float* A_log_b = (const float*)d_in[14];
    const float* Dp_b    = (const float*)d_in[15];
    const float* W_out   = (const float*)d_in[16];
    float* out = (float*)d_out;

    char* ws = (char*)d_ws;
    ushort_t* xz16  = (ushort_t*)(ws + OFF_XZ16);
    ushort_t* xc16  = (ushort_t*)(ws + OFF_XC16);
    ushort_t* dbc16 = (ushort_t*)(ws + OFF_DBC16);
    ushort_t* delta = (ushort_t*)(ws + OFF_DELTA);
    ushort_t* yf    = (ushort_t*)(ws + OFF_YF);
    ushort_t* yb    = (ushort_t*)(ws + OFF_YB);
    ushort_t* x16   = (ushort_t*)(ws + OFF_X16);
    ushort_t* win16 = (ushort_t*)(ws + OFF_WIN16);
    ushort_t* wx16  = (ushort_t*)(ws + OFF_WX16);
    ushort_t* wdt16 = (ushort_t*)(ws + OFF_WDT16);
    ushort_t* wout16= (ushort_t*)(ws + OFF_WOUT16);
    float*    part  = (float*)(ws + OFF_PART);
    float*    p01   = (float*)(ws + OFF_DELTA);   // delta dead after scan (16MB)
    float*    p23   = (float*)(ws + OFF_YC16);    // yc16+x16+win16 dead (20MB span)

    dim3 blk(256);

    CastArgs ca;
    const int n4s[7] = {524288, 1048576, 49152, 49152, 32768, 32768, 524288};
    ca.seg[0] = { (const float4*)x,     (ushort4*)x16 };
    ca.seg[1] = { (const float4*)W_in,  (ushort4*)win16 };
    ca.seg[2] = { (const float4*)Wx,    (ushort4*)wx16 };
    ca.seg[3] = { (const float4*)Wx_b,  (ushort4*)(wx16 + 96 * 2048) };
    ca.seg[4] = { (const float4*)Wdt,   (ushort4*)wdt16 };
    ca.seg[5] = { (const float4*)Wdt_b, (ushort4*)(wdt16 + 2048 * 64) };
    ca.seg[6] = { (const float4*)W_out, (ushort4*)wout16 };
    ca.start[0] = 0;
    for (int i = 0; i < 7; i++) ca.start[i + 1] = ca.start[i] + n4s[i];
    cast_multi<<<(ca.start[7] + 255) / 256, blk, 0, stream>>>(ca);

    gemm_g1<<<dim3(32, 32), blk, 0, stream>>>(x16, 1024, win16, 1024, xz16, 4096, 1024);

    conv_silu_kernel<<<4096, blk, 0, stream>>>(xz16, conv_w, conv_b, conv_w_b, conv_b_b, xc16);

    gemm_g2<<<dim3(8, 32, 2), blk, 0, stream>>>(xc16, wx16, part);
    reduce_dbc<<<384, blk, 0, stream>>>((const float4*)part, (ushort4*)dbc16);

    gemm_g3<<<dim3(16, 32, 2), blk, 0, stream>>>(dbc16, wdt16, delta, b_dt, b_dt_b);

    scan_kernel<<<512, blk, 0, stream>>>(delta, xc16, dbc16, xz16, A_log, A_log_b, Dp, Dp_b, yf, yb);

    gemm_g4<<<dim3(8, 32, 4), blk, 0, stream>>>(yf, yb, wout16, 2048, p01, p23);
    reduce_g4<<<2048, blk, 0, stream>>>((const float4*)p01, (const float4*)p23, (float4*)out);
}